// Round 1
// baseline (1377.081 us; speedup 1.0000x reference)
//
#include <hip/hip_runtime.h>
#include <stdint.h>
#include <math.h>

typedef unsigned short u16;
typedef __attribute__((ext_vector_type(4))) float f32x4;
typedef __attribute__((ext_vector_type(8))) short s16x8;

#define U_N 8192
#define E_N 200000
#define D_N 768
#define DE_N 50
#define KP_E 832
#define BN_EPS 1e-5f

__device__ __forceinline__ u16 f2bf(float f) {
  union { float f; unsigned u; } v; v.f = f;
  return (u16)((v.u + 0x7fffu + ((v.u >> 16) & 1u)) >> 16);
}

// LDS tile [128 rows][32 k] bf16, 16B-slot XOR swizzle: slot' = slot ^ ((r>>1)&3)
__device__ __forceinline__ int lds_idx(int r, int k) {
  return r * 32 + (((k >> 3) ^ ((r >> 1) & 3)) * 8) + (k & 7);
}

// ---------------- searchsorted (left) ----------------
__global__ void k_localidx(const int* __restrict__ uniq, const int* __restrict__ src,
                           int* __restrict__ lidx) {
  int e = blockIdx.x * 256 + threadIdx.x;
  if (e >= E_N) return;
  int v = src[e];
  int lo = 0, hi = U_N;
  while (lo < hi) { int mid = (lo + hi) >> 1; if (uniq[mid] < v) lo = mid + 1; else hi = mid; }
  lidx[e] = lo;
}

// ---------------- weight conversions ----------------
__global__ void k_conv_wedge(const float* __restrict__ W, u16* __restrict__ Wb) {
  int i = blockIdx.x * 256 + threadIdx.x;
  if (i >= D_N * KP_E) return;
  int n = i / KP_E, k = i % KP_E;
  float f = (k < D_N + DE_N) ? W[n * (D_N + DE_N) + k] : 0.f;
  Wb[i] = f2bf(f);
}

__global__ void k_conv_w(const float* __restrict__ W, u16* __restrict__ Wb, int count) {
  int i = blockIdx.x * 256 + threadIdx.x;
  if (i < count) Wb[i] = f2bf(W[i]);
}

// ---------------- edge GEMM + relu + atomic scatter ----------------
__global__ __launch_bounds__(256)
void gemm_edge(const float* __restrict__ tgt, const float* __restrict__ edg,
               const u16* __restrict__ Wb, const float* __restrict__ bias,
               const int* __restrict__ lidx, float* __restrict__ agg) {
  __shared__ u16 As[128 * 32];
  __shared__ u16 Bs[128 * 32];
  const int t = threadIdx.x;
  const int bm = (blockIdx.x / 6) * 128;
  const int bn = (blockIdx.x % 6) * 128;
  const int wave = t >> 6, lane = t & 63;
  const int wr = (wave & 1) * 64, wc = (wave >> 1) * 64;
  const int sr = t >> 1, sp = (t & 1) * 2;
  const int e_st = bm + sr;
  f32x4 acc[4][4] = {};
  for (int k0 = 0; k0 < KP_E; k0 += 32) {
    // stage A (edges x k), fp32 -> bf16, zero-pad k>=818 and rows >= E
#pragma unroll
    for (int s2 = 0; s2 < 2; s2++) {
      const int s = sp + s2;
      const int kg = k0 + s * 8;
      s16x8 v = {};
      if (e_st < E_N) {
        if (kg + 8 <= D_N) {
          const f32x4 f0 = *(const f32x4*)(tgt + (size_t)e_st * D_N + kg);
          const f32x4 f1 = *(const f32x4*)(tgt + (size_t)e_st * D_N + kg + 4);
#pragma unroll
          for (int z = 0; z < 4; z++) { v[z] = (short)f2bf(f0[z]); v[4 + z] = (short)f2bf(f1[z]); }
        } else {
#pragma unroll
          for (int z = 0; z < 8; z++) {
            const int kk = kg + z - D_N;
            v[z] = (short)f2bf(kk < DE_N ? edg[(size_t)e_st * DE_N + kk] : 0.f);
          }
        }
      }
      *(s16x8*)&As[lds_idx(sr, s * 8)] = v;
    }
    // stage B from pre-converted padded Wb [768][832]
    {
      const u16* gb = Wb + (size_t)(bn + sr) * KP_E + k0 + sp * 8;
      const s16x8 w0 = *(const s16x8*)gb;
      const s16x8 w1 = *(const s16x8*)(gb + 8);
      *(s16x8*)&Bs[lds_idx(sr, sp * 8)] = w0;
      *(s16x8*)&Bs[lds_idx(sr, (sp + 1) * 8)] = w1;
    }
    __syncthreads();
    s16x8 af[4], bfr[4];
    const int rl = lane & 15, kl = (lane >> 4) * 8;
#pragma unroll
    for (int i = 0; i < 4; i++) af[i] = *(const s16x8*)&As[lds_idx(wr + i * 16 + rl, kl)];
#pragma unroll
    for (int j = 0; j < 4; j++) bfr[j] = *(const s16x8*)&Bs[lds_idx(wc + j * 16 + rl, kl)];
#pragma unroll
    for (int i = 0; i < 4; i++)
#pragma unroll
      for (int j = 0; j < 4; j++)
        acc[i][j] = __builtin_amdgcn_mfma_f32_16x16x32_bf16(af[i], bfr[j], acc[i][j], 0, 0, 0);
    __syncthreads();
  }
  // epilogue: relu(acc + bias) then atomic scatter into agg[lidx[e]]
  const int cl = lane & 15, rq = (lane >> 4) * 4;
#pragma unroll
  for (int j = 0; j < 4; j++) {
    const int n = bn + wc + j * 16 + cl;
    const float bj = bias[n];
#pragma unroll
    for (int i = 0; i < 4; i++) {
      const int r0 = bm + wr + i * 16 + rq;
#pragma unroll
      for (int q = 0; q < 4; q++) {
        const int e = r0 + q;
        if (e < E_N) {
          const float val = acc[i][j][q] + bj;
          if (val > 0.f) atomicAdd(&agg[(size_t)lidx[e] * D_N + n], val);
        }
      }
    }
  }
}

// ---------------- generic bf16 GEMM (A [M][K], B [N][K], C f32 [M][N]) ----------------
__global__ __launch_bounds__(256)
void gemm_bf16(const u16* __restrict__ A, const u16* __restrict__ B,
               float* __restrict__ C, int M, int N, int K) {
  __shared__ u16 As[128 * 32];
  __shared__ u16 Bs[128 * 32];
  const int t = threadIdx.x;
  const int ntn = N >> 7;
  const int bm = (blockIdx.x / ntn) * 128;
  const int bn = (blockIdx.x % ntn) * 128;
  const int wave = t >> 6, lane = t & 63;
  const int wr = (wave & 1) * 64, wc = (wave >> 1) * 64;
  const int sr = t >> 1, sp = (t & 1) * 2;
  f32x4 acc[4][4] = {};
  for (int k0 = 0; k0 < K; k0 += 32) {
    {
      const u16* ga = A + (size_t)(bm + sr) * K + k0 + sp * 8;
      const s16x8 a0 = *(const s16x8*)ga;
      const s16x8 a1 = *(const s16x8*)(ga + 8);
      *(s16x8*)&As[lds_idx(sr, sp * 8)] = a0;
      *(s16x8*)&As[lds_idx(sr, (sp + 1) * 8)] = a1;
      const u16* gb = B + (size_t)(bn + sr) * K + k0 + sp * 8;
      const s16x8 b0 = *(const s16x8*)gb;
      const s16x8 b1 = *(const s16x8*)(gb + 8);
      *(s16x8*)&Bs[lds_idx(sr, sp * 8)] = b0;
      *(s16x8*)&Bs[lds_idx(sr, (sp + 1) * 8)] = b1;
    }
    __syncthreads();
    s16x8 af[4], bfr[4];
    const int rl = lane & 15, kl = (lane >> 4) * 8;
#pragma unroll
    for (int i = 0; i < 4; i++) af[i] = *(const s16x8*)&As[lds_idx(wr + i * 16 + rl, kl)];
#pragma unroll
    for (int j = 0; j < 4; j++) bfr[j] = *(const s16x8*)&Bs[lds_idx(wc + j * 16 + rl, kl)];
#pragma unroll
    for (int i = 0; i < 4; i++)
#pragma unroll
      for (int j = 0; j < 4; j++)
        acc[i][j] = __builtin_amdgcn_mfma_f32_16x16x32_bf16(af[i], bfr[j], acc[i][j], 0, 0, 0);
    __syncthreads();
  }
  const int cl = lane & 15, rq = (lane >> 4) * 4;
#pragma unroll
  for (int i = 0; i < 4; i++)
#pragma unroll
    for (int j = 0; j < 4; j++) {
      const int n = bn + wc + j * 16 + cl;
      const int r = bm + wr + i * 16 + rq;
#pragma unroll
      for (int q = 0; q < 4; q++)
        C[(size_t)(r + q) * N + n] = acc[i][j][q];
    }
}

// ---------------- GIN combine: h = (1+eps)*x + agg -> bf16 ----------------
__global__ void k_build_h(const float* __restrict__ x, const float* __restrict__ agg,
                          const float* __restrict__ epsp, u16* __restrict__ hbf) {
  int i = blockIdx.x * 256 + threadIdx.x;
  if (i >= U_N * D_N) return;
  float h = (1.f + epsp[0]) * x[i] + agg[i];
  hbf[i] = f2bf(h);
}

// ---------------- BN stats ----------------
__global__ void k_bnstats(const float* __restrict__ h1, float* __restrict__ ssum,
                          float* __restrict__ ssq) {
  const int cchunk = blockIdx.x % 3;
  const int rchunk = blockIdx.x / 3;
  const int c = cchunk * 256 + threadIdx.x;
  const int r0 = rchunk * 256;
  float s = 0.f, s2 = 0.f;
  for (int r = r0; r < r0 + 256; r++) {
    float v = h1[(size_t)r * D_N + c];
    s += v; s2 += v * v;
  }
  atomicAdd(&ssum[c], s);
  atomicAdd(&ssq[c], s2);
}

__global__ void k_bnfinal(const float* __restrict__ ssum, const float* __restrict__ ssq,
                          const float* __restrict__ gamma, const float* __restrict__ beta,
                          float* __restrict__ scale, float* __restrict__ shift) {
  int c = blockIdx.x * 256 + threadIdx.x;
  if (c >= D_N) return;
  double mean = (double)ssum[c] / (double)U_N;
  double var = (double)ssq[c] / (double)U_N - mean * mean;
  float sc = (float)((double)gamma[c] / sqrt(var + (double)BN_EPS));
  scale[c] = sc;
  shift[c] = beta[c] - (float)mean * sc;
}

__global__ void k_bnapply(const float* __restrict__ h1, const float* __restrict__ scale,
                          const float* __restrict__ shift, u16* __restrict__ h2) {
  int i = blockIdx.x * 256 + threadIdx.x;
  if (i >= U_N * D_N) return;
  int c = i % D_N;
  float v = h1[i] * scale[c] + shift[c];
  h2[i] = f2bf(v > 0.f ? v : 0.f);
}

extern "C" void kernel_launch(void* const* d_in, const int* in_sizes, int n_in,
                              void* d_out, int out_size, void* d_ws, size_t ws_size,
                              hipStream_t stream) {
  const float* x     = (const float*)d_in[0];
  const int*   uniq  = (const int*)d_in[1];
  const int*   srcg  = (const int*)d_in[2];
  const float* tgt   = (const float*)d_in[3];
  const float* edg   = (const float*)d_in[4];
  const float* Wedge = (const float*)d_in[5];
  const float* bedge = (const float*)d_in[6];
  const float* W1    = (const float*)d_in[7];
  const float* W2    = (const float*)d_in[8];
  const float* gamma = (const float*)d_in[9];
  const float* beta  = (const float*)d_in[10];
  const float* epsp  = (const float*)d_in[11];
  float* out = (float*)d_out;

  char* ws = (char*)d_ws;
  float* agg   = (float*)(ws + 0);          // 25165824 B
  float* h1    = (float*)(ws + 25165824);   // 25165824 B
  u16*   web   = (u16*)  (ws + 50331648);   // 1277952 B
  u16*   w1b   = (u16*)  (ws + 51609600);   // 1179648 B
  u16*   w2b   = (u16*)  (ws + 52789248);   // 1179648 B
  u16*   hbf   = (u16*)  (ws + 53968896);   // 12582912 B
  u16*   h2b   = (u16*)  (ws + 66551808);   // 12582912 B
  int*   lidx  = (int*)  (ws + 79134720);   // 800000 B
  float* ssum  = (float*)(ws + 79934720);   // 3072 B
  float* ssq   = (float*)(ws + 79937792);   // 3072 B
  float* scale = (float*)(ws + 79940864);   // 3072 B
  float* shift = (float*)(ws + 79943936);   // 3072 B

  hipMemsetAsync(agg, 0, (size_t)U_N * D_N * 4, stream);
  hipMemsetAsync(ssum, 0, 2 * D_N * 4, stream);  // ssum + ssq contiguous

  k_localidx<<<(E_N + 255) / 256, 256, 0, stream>>>(uniq, srcg, lidx);
  k_conv_wedge<<<(D_N * KP_E + 255) / 256, 256, 0, stream>>>(Wedge, web);
  k_conv_w<<<(D_N * D_N + 255) / 256, 256, 0, stream>>>(W1, w1b, D_N * D_N);
  k_conv_w<<<(D_N * D_N + 255) / 256, 256, 0, stream>>>(W2, w2b, D_N * D_N);

  // edge GEMM + scatter: M-tiles = ceil(200000/128) = 1563, N-tiles = 6
  gemm_edge<<<1563 * 6, 256, 0, stream>>>(tgt, edg, web, bedge, lidx, agg);

  k_build_h<<<(U_N * D_N + 255) / 256, 256, 0, stream>>>(x, agg, epsp, hbf);

  // h1 = h @ W1^T
  gemm_bf16<<<(U_N / 128) * (D_N / 128), 256, 0, stream>>>(hbf, w1b, h1, U_N, D_N, D_N);

  k_bnstats<<<96, 256, 0, stream>>>(h1, ssum, ssq);
  k_bnfinal<<<3, 256, 0, stream>>>(ssum, ssq, gamma, beta, scale, shift);
  k_bnapply<<<(U_N * D_N + 255) / 256, 256, 0, stream>>>(h1, scale, shift, h2b);

  // out = relu(bn(h1)) @ W2^T
  gemm_bf16<<<(U_N / 128) * (D_N / 128), 256, 0, stream>>>(h2b, w2b, out, U_N, D_N, D_N);
}

// Round 2
// 875.728 us; speedup vs baseline: 1.5725x; 1.5725x over previous
//
#include <hip/hip_runtime.h>
#include <stdint.h>
#include <math.h>

typedef unsigned short u16;
typedef __attribute__((ext_vector_type(4))) float f32x4;
typedef __attribute__((ext_vector_type(8))) short s16x8;

#define U_N 8192
#define E_N 200000
#define M_PAD 200192   // 1564 * 128
#define NMT 1564
#define D_N 768
#define DE_N 50
#define KP_E 832
#define BN_EPS 1e-5f

__device__ __forceinline__ u16 f2bf(float f) {
  union { float f; unsigned u; } v; v.f = f;
  return (u16)((v.u + 0x7fffu + ((v.u >> 16) & 1u)) >> 16);
}
__device__ __forceinline__ float bf2f(u16 v) {
  union { unsigned u; float f; } x; x.u = ((unsigned)v) << 16; return x.f;
}
__device__ __forceinline__ void gload16(const void* g, void* l) {
  __builtin_amdgcn_global_load_lds((const __attribute__((address_space(1))) void*)g,
                                   (__attribute__((address_space(3))) void*)l, 16, 0, 0);
}

// legacy swizzled LDS index (fallback path)
__device__ __forceinline__ int lds_idx(int r, int k) {
  return r * 32 + (((k >> 3) ^ ((r >> 1) & 3)) * 8) + (k & 7);
}

// ---------------- searchsorted (left) ----------------
__global__ void k_localidx(const int* __restrict__ uniq, const int* __restrict__ src,
                           int* __restrict__ lidx) {
  int e = blockIdx.x * 256 + threadIdx.x;
  if (e >= E_N) return;
  int v = src[e];
  int lo = 0, hi = U_N;
  while (lo < hi) { int mid = (lo + hi) >> 1; if (uniq[mid] < v) lo = mid + 1; else hi = mid; }
  lidx[e] = lo;
}

// ---------------- counting sort: hist / scan / scatter ----------------
__global__ void k_hist(const int* __restrict__ lidx, int* __restrict__ counts) {
  int e = blockIdx.x * 256 + threadIdx.x;
  if (e < E_N) atomicAdd(&counts[lidx[e]], 1);
}

__global__ void k_scan(const int* __restrict__ counts, int* __restrict__ starts) {
  __shared__ int part[1024];
  const int t = threadIdx.x;
  const int base = t * 8;
  int loc[8]; int s = 0;
#pragma unroll
  for (int i = 0; i < 8; i++) { loc[i] = s; s += counts[base + i]; }
  part[t] = s; __syncthreads();
  for (int off = 1; off < 1024; off <<= 1) {
    int v = (t >= off) ? part[t - off] : 0;
    __syncthreads();
    part[t] += v;
    __syncthreads();
  }
  const int pre = (t == 0) ? 0 : part[t - 1];
#pragma unroll
  for (int i = 0; i < 8; i++) starts[base + i] = pre + loc[i];
  if (t == 1023) starts[8192] = pre + s;
}

__global__ void k_scatter(const int* __restrict__ lidx, const int* __restrict__ starts,
                          int* __restrict__ cursor, int* __restrict__ eord) {
  int e = blockIdx.x * 256 + threadIdx.x;
  if (e >= E_N) return;
  int u = lidx[e];
  int pos = atomicAdd(&cursor[u], 1);
  eord[starts[u] + pos] = e;
}

// ---------------- pack A: [E][832] bf16, concat(tgt, edg, 0-pad) ----------------
__global__ void k_pack(const float* __restrict__ tgt, const float* __restrict__ edg,
                       u16* __restrict__ Abf) {
  const long long g = (long long)blockIdx.x * 256 + threadIdx.x;
  if (g >= (long long)E_N * 104) return;
  const int e = (int)(g / 104), seg = (int)(g % 104);
  const int c0 = seg * 8;
  s16x8 v = {};
  if (c0 + 8 <= D_N) {
    const f32x4 f0 = *(const f32x4*)(tgt + (size_t)e * D_N + c0);
    const f32x4 f1 = *(const f32x4*)(tgt + (size_t)e * D_N + c0 + 4);
#pragma unroll
    for (int z = 0; z < 4; z++) { v[z] = (short)f2bf(f0[z]); v[4 + z] = (short)f2bf(f1[z]); }
  } else {
#pragma unroll
    for (int z = 0; z < 8; z++) {
      const int kk = c0 + z - D_N;
      v[z] = (short)f2bf(kk < DE_N ? edg[(size_t)e * DE_N + kk] : 0.f);
    }
  }
  *(s16x8*)&Abf[(size_t)e * KP_E + c0] = v;
}

// ---------------- weight conversions ----------------
__global__ void k_conv_wedge(const float* __restrict__ W, u16* __restrict__ Wb) {
  int i = blockIdx.x * 256 + threadIdx.x;
  if (i >= D_N * KP_E) return;
  int n = i / KP_E, k = i % KP_E;
  float f = (k < D_N + DE_N) ? W[n * (D_N + DE_N) + k] : 0.f;
  Wb[i] = f2bf(f);
}

__global__ void k_conv_w(const float* __restrict__ W, u16* __restrict__ Wb, int count) {
  int i = blockIdx.x * 256 + threadIdx.x;
  if (i < count) Wb[i] = f2bf(W[i]);
}

// ---------------- edge GEMM (m97 structure): msgs = relu(Abf·Wb^T + bias) ----------------
__global__ __launch_bounds__(256)
void gemm_edge2(const u16* __restrict__ Abf, const u16* __restrict__ Wb,
                const float* __restrict__ bias, u16* __restrict__ msgs) {
  __shared__ u16 As[128 * 64];
  __shared__ u16 Bs[128 * 64];
  // XCD-aware decode: same-M-panel N-tiles cluster on one XCD
  const int xq = NMT / 8, xr = NMT % 8;            // 195, 4
  const int x = blockIdx.x & 7;
  const int i0 = blockIdx.x >> 3;
  const int mcount = xq + (x < xr ? 1 : 0);
  if (i0 >= mcount * 6) return;
  const int mstart = x * xq + (x < xr ? x : xr);
  const int bm = (mstart + i0 / 6) * 128;
  const int bn = (i0 % 6) * 128;

  const int t = threadIdx.x;
  const int wave = t >> 6, lane = t & 63;
  const int wr = (wave & 1) * 64, wc = (wave >> 1) * 64;
  const int srow = lane >> 3;          // row within 8-row chunk
  const int scol = (lane & 7) * 8;     // elem col within 64
  const int rl = lane & 15, kl = (lane >> 4) * 8;
  f32x4 acc[4][4] = {};

  for (int k0 = 0; k0 < KP_E; k0 += 64) {
#pragma unroll
    for (int q = 0; q < 4; q++) {
      const int c = wave * 4 + q;            // 16 chunks of 8 rows
      const int row = c * 8 + srow;
      gload16(Abf + (size_t)(bm + row) * KP_E + k0 + scol, As + c * 512);
      gload16(Wb + (size_t)(bn + row) * KP_E + k0 + scol, Bs + c * 512);
    }
    __syncthreads();
#pragma unroll
    for (int ks = 0; ks < 2; ks++) {
      s16x8 af[4], bfr[4];
#pragma unroll
      for (int i = 0; i < 4; i++) af[i] = *(const s16x8*)&As[(wr + i * 16 + rl) * 64 + ks * 32 + kl];
#pragma unroll
      for (int j = 0; j < 4; j++) bfr[j] = *(const s16x8*)&Bs[(wc + j * 16 + rl) * 64 + ks * 32 + kl];
#pragma unroll
      for (int i = 0; i < 4; i++)
#pragma unroll
        for (int j = 0; j < 4; j++)
          acc[i][j] = __builtin_amdgcn_mfma_f32_16x16x32_bf16(af[i], bfr[j], acc[i][j], 0, 0, 0);
    }
    __syncthreads();
  }
  const int cl = lane & 15, rq = (lane >> 4) * 4;
#pragma unroll
  for (int j = 0; j < 4; j++) {
    const int n = bn + wc + j * 16 + cl;
    const float bj = bias[n];
#pragma unroll
    for (int i = 0; i < 4; i++) {
      const int r0 = bm + wr + i * 16 + rq;
#pragma unroll
      for (int q = 0; q < 4; q++) {
        const float val = acc[i][j][q] + bj;
        msgs[(size_t)(r0 + q) * D_N + n] = f2bf(val > 0.f ? val : 0.f);
      }
    }
  }
}

// ---------------- gather: h = (1+eps)*x + segment_sum(msgs) -> bf16 ----------------
__global__ __launch_bounds__(384)
void k_gather(const u16* __restrict__ msgs, const int* __restrict__ starts,
              const int* __restrict__ eord, const float* __restrict__ x,
              const float* __restrict__ epsp, u16* __restrict__ hbf) {
  const int u = blockIdx.x;
  const int c2 = threadIdx.x;            // col pair: cols 2*c2, 2*c2+1
  const int s = starts[u], e = starts[u + 1];
  float a0 = 0.f, a1 = 0.f;
  for (int i = s; i < e; i++) {
    const unsigned v = *(const unsigned*)&msgs[(size_t)eord[i] * D_N + c2 * 2];
    a0 += bf2f((u16)(v & 0xffffu));
    a1 += bf2f((u16)(v >> 16));
  }
  const float ep = 1.f + epsp[0];
  const float2 xv = *(const float2*)&x[(size_t)u * D_N + c2 * 2];
  const unsigned o = ((unsigned)f2bf(ep * xv.y + a1) << 16) | (unsigned)f2bf(ep * xv.x + a0);
  *(unsigned*)&hbf[(size_t)u * D_N + c2 * 2] = o;
}

// ---------------- generic bf16 GEMM (m97 structure), C f32 [M][N], K%64==0 ----------------
__global__ __launch_bounds__(256)
void gemm_bf16_g(const u16* __restrict__ A, const u16* __restrict__ B,
                 float* __restrict__ C, int ntn, int K) {
  __shared__ u16 As[128 * 64];
  __shared__ u16 Bs[128 * 64];
  const int bm = (blockIdx.x / ntn) * 128;
  const int bn = (blockIdx.x % ntn) * 128;
  const int t = threadIdx.x;
  const int wave = t >> 6, lane = t & 63;
  const int wr = (wave & 1) * 64, wc = (wave >> 1) * 64;
  const int srow = lane >> 3, scol = (lane & 7) * 8;
  const int rl = lane & 15, kl = (lane >> 4) * 8;
  const int N = ntn * 128;
  f32x4 acc[4][4] = {};
  for (int k0 = 0; k0 < K; k0 += 64) {
#pragma unroll
    for (int q = 0; q < 4; q++) {
      const int c = wave * 4 + q;
      const int row = c * 8 + srow;
      gload16(A + (size_t)(bm + row) * K + k0 + scol, As + c * 512);
      gload16(B + (size_t)(bn + row) * K + k0 + scol, Bs + c * 512);
    }
    __syncthreads();
#pragma unroll
    for (int ks = 0; ks < 2; ks++) {
      s16x8 af[4], bfr[4];
#pragma unroll
      for (int i = 0; i < 4; i++) af[i] = *(const s16x8*)&As[(wr + i * 16 + rl) * 64 + ks * 32 + kl];
#pragma unroll
      for (int j = 0; j < 4; j++) bfr[j] = *(const s16x8*)&Bs[(wc + j * 16 + rl) * 64 + ks * 32 + kl];
#pragma unroll
      for (int i = 0; i < 4; i++)
#pragma unroll
        for (int j = 0; j < 4; j++)
          acc[i][j] = __builtin_amdgcn_mfma_f32_16x16x32_bf16(af[i], bfr[j], acc[i][j], 0, 0, 0);
    }
    __syncthreads();
  }
  const int cl = lane & 15, rq = (lane >> 4) * 4;
#pragma unroll
  for (int i = 0; i < 4; i++)
#pragma unroll
    for (int j = 0; j < 4; j++) {
      const int n = bn + wc + j * 16 + cl;
      const int r = bm + wr + i * 16 + rq;
#pragma unroll
      for (int q = 0; q < 4; q++)
        C[(size_t)(r + q) * N + n] = acc[i][j][q];
    }
}

// ---------------- BN ----------------
__global__ void k_bnstats(const float* __restrict__ h1, float* __restrict__ ssum,
                          float* __restrict__ ssq) {
  const int cchunk = blockIdx.x % 3;
  const int rchunk = blockIdx.x / 3;
  const int c = cchunk * 256 + threadIdx.x;
  const int r0 = rchunk * 256;
  float s = 0.f, s2 = 0.f;
  for (int r = r0; r < r0 + 256; r++) {
    float v = h1[(size_t)r * D_N + c];
    s += v; s2 += v * v;
  }
  atomicAdd(&ssum[c], s);
  atomicAdd(&ssq[c], s2);
}

__global__ void k_bnfinal(const float* __restrict__ ssum, const float* __restrict__ ssq,
                          const float* __restrict__ gamma, const float* __restrict__ beta,
                          float* __restrict__ scale, float* __restrict__ shift) {
  int c = blockIdx.x * 256 + threadIdx.x;
  if (c >= D_N) return;
  double mean = (double)ssum[c] / (double)U_N;
  double var = (double)ssq[c] / (double)U_N - mean * mean;
  float sc = (float)((double)gamma[c] / sqrt(var + (double)BN_EPS));
  scale[c] = sc;
  shift[c] = beta[c] - (float)mean * sc;
}

__global__ void k_bnapply(const float* __restrict__ h1, const float* __restrict__ scale,
                          const float* __restrict__ shift, u16* __restrict__ h2) {
  int i = blockIdx.x * 256 + threadIdx.x;
  if (i >= U_N * D_N) return;
  int c = i % D_N;
  float v = h1[i] * scale[c] + shift[c];
  h2[i] = f2bf(v > 0.f ? v : 0.f);
}

// ================= FALLBACK PATH (round-1, ~80 MB ws) =================
__global__ __launch_bounds__(256)
void gemm_edge_fb(const float* __restrict__ tgt, const float* __restrict__ edg,
                  const u16* __restrict__ Wb, const float* __restrict__ bias,
                  const int* __restrict__ lidx, float* __restrict__ agg) {
  __shared__ u16 As[128 * 32];
  __shared__ u16 Bs[128 * 32];
  const int t = threadIdx.x;
  const int bm = (blockIdx.x / 6) * 128;
  const int bn = (blockIdx.x % 6) * 128;
  const int wave = t >> 6, lane = t & 63;
  const int wr = (wave & 1) * 64, wc = (wave >> 1) * 64;
  const int sr = t >> 1, sp = (t & 1) * 2;
  const int e_st = bm + sr;
  f32x4 acc[4][4] = {};
  for (int k0 = 0; k0 < KP_E; k0 += 32) {
#pragma unroll
    for (int s2 = 0; s2 < 2; s2++) {
      const int s = sp + s2;
      const int kg = k0 + s * 8;
      s16x8 v = {};
      if (e_st < E_N) {
        if (kg + 8 <= D_N) {
          const f32x4 f0 = *(const f32x4*)(tgt + (size_t)e_st * D_N + kg);
          const f32x4 f1 = *(const f32x4*)(tgt + (size_t)e_st * D_N + kg + 4);
#pragma unroll
          for (int z = 0; z < 4; z++) { v[z] = (short)f2bf(f0[z]); v[4 + z] = (short)f2bf(f1[z]); }
        } else {
#pragma unroll
          for (int z = 0; z < 8; z++) {
            const int kk = kg + z - D_N;
            v[z] = (short)f2bf(kk < DE_N ? edg[(size_t)e_st * DE_N + kk] : 0.f);
          }
        }
      }
      *(s16x8*)&As[lds_idx(sr, s * 8)] = v;
    }
    {
      const u16* gb = Wb + (size_t)(bn + sr) * KP_E + k0 + sp * 8;
      const s16x8 w0 = *(const s16x8*)gb;
      const s16x8 w1 = *(const s16x8*)(gb + 8);
      *(s16x8*)&Bs[lds_idx(sr, sp * 8)] = w0;
      *(s16x8*)&Bs[lds_idx(sr, (sp + 1) * 8)] = w1;
    }
    __syncthreads();
    s16x8 af[4], bfr[4];
    const int rl = lane & 15, kl = (lane >> 4) * 8;
#pragma unroll
    for (int i = 0; i < 4; i++) af[i] = *(const s16x8*)&As[lds_idx(wr + i * 16 + rl, kl)];
#pragma unroll
    for (int j = 0; j < 4; j++) bfr[j] = *(const s16x8*)&Bs[lds_idx(wc + j * 16 + rl, kl)];
#pragma unroll
    for (int i = 0; i < 4; i++)
#pragma unroll
      for (int j = 0; j < 4; j++)
        acc[i][j] = __builtin_amdgcn_mfma_f32_16x16x32_bf16(af[i], bfr[j], acc[i][j], 0, 0, 0);
    __syncthreads();
  }
  const int cl = lane & 15, rq = (lane >> 4) * 4;
#pragma unroll
  for (int j = 0; j < 4; j++) {
    const int n = bn + wc + j * 16 + cl;
    const float bj = bias[n];
#pragma unroll
    for (int i = 0; i < 4; i++) {
      const int r0 = bm + wr + i * 16 + rq;
#pragma unroll
      for (int q = 0; q < 4; q++) {
        const int e = r0 + q;
        if (e < E_N) {
          const float val = acc[i][j][q] + bj;
          if (val > 0.f) atomicAdd(&agg[(size_t)lidx[e] * D_N + n], val);
        }
      }
    }
  }
}

__global__ void k_build_h(const float* __restrict__ x, const float* __restrict__ agg,
                          const float* __restrict__ epsp, u16* __restrict__ hbf) {
  int i = blockIdx.x * 256 + threadIdx.x;
  if (i >= U_N * D_N) return;
  float h = (1.f + epsp[0]) * x[i] + agg[i];
  hbf[i] = f2bf(h);
}

__global__ __launch_bounds__(256)
void gemm_bf16_fb(const u16* __restrict__ A, const u16* __restrict__ B,
                  float* __restrict__ C, int M, int N, int K) {
  __shared__ u16 As[128 * 32];
  __shared__ u16 Bs[128 * 32];
  const int t = threadIdx.x;
  const int ntn = N >> 7;
  const int bm = (blockIdx.x / ntn) * 128;
  const int bn = (blockIdx.x % ntn) * 128;
  const int wave = t >> 6, lane = t & 63;
  const int wr = (wave & 1) * 64, wc = (wave >> 1) * 64;
  const int sr = t >> 1, sp = (t & 1) * 2;
  f32x4 acc[4][4] = {};
  for (int k0 = 0; k0 < K; k0 += 32) {
    {
      const u16* ga = A + (size_t)(bm + sr) * K + k0 + sp * 8;
      const s16x8 a0 = *(const s16x8*)ga;
      const s16x8 a1 = *(const s16x8*)(ga + 8);
      *(s16x8*)&As[lds_idx(sr, sp * 8)] = a0;
      *(s16x8*)&As[lds_idx(sr, (sp + 1) * 8)] = a1;
      const u16* gb = B + (size_t)(bn + sr) * K + k0 + sp * 8;
      const s16x8 b0 = *(const s16x8*)gb;
      const s16x8 b1 = *(const s16x8*)(gb + 8);
      *(s16x8*)&Bs[lds_idx(sr, sp * 8)] = b0;
      *(s16x8*)&Bs[lds_idx(sr, (sp + 1) * 8)] = b1;
    }
    __syncthreads();
    s16x8 af[4], bfr[4];
    const int rl = lane & 15, kl = (lane >> 4) * 8;
#pragma unroll
    for (int i = 0; i < 4; i++) af[i] = *(const s16x8*)&As[lds_idx(wr + i * 16 + rl, kl)];
#pragma unroll
    for (int j = 0; j < 4; j++) bfr[j] = *(const s16x8*)&Bs[lds_idx(wc + j * 16 + rl, kl)];
#pragma unroll
    for (int i = 0; i < 4; i++)
#pragma unroll
      for (int j = 0; j < 4; j++)
        acc[i][j] = __builtin_amdgcn_mfma_f32_16x16x32_bf16(af[i], bfr[j], acc[i][j], 0, 0, 0);
    __syncthreads();
  }
  const int cl = lane & 15, rq = (lane >> 4) * 4;
#pragma unroll
  for (int i = 0; i < 4; i++)
#pragma unroll
    for (int j = 0; j < 4; j++) {
      const int n = bn + wc + j * 16 + cl;
      const int r = bm + wr + i * 16 + rq;
#pragma unroll
      for (int q = 0; q < 4; q++)
        C[(size_t)(r + q) * N + n] = acc[i][j][q];
    }
}

extern "C" void kernel_launch(void* const* d_in, const int* in_sizes, int n_in,
                              void* d_out, int out_size, void* d_ws, size_t ws_size,
                              hipStream_t stream) {
  const float* x     = (const float*)d_in[0];
  const int*   uniq  = (const int*)d_in[1];
  const int*   srcg  = (const int*)d_in[2];
  const float* tgt   = (const float*)d_in[3];
  const float* edg   = (const float*)d_in[4];
  const float* Wedge = (const float*)d_in[5];
  const float* bedge = (const float*)d_in[6];
  const float* W1    = (const float*)d_in[7];
  const float* W2    = (const float*)d_in[8];
  const float* gamma = (const float*)d_in[9];
  const float* beta  = (const float*)d_in[10];
  const float* epsp  = (const float*)d_in[11];
  float* out = (float*)d_out;
  char* ws = (char*)d_ws;

  const size_t NEED = 700ull * 1024 * 1024;
  if (ws_size >= NEED) {
    // ---------- primary path ----------
    u16*   Abf   = (u16*)  (ws + 0);            // 333,119,488
    u16*   msgs  = (u16*)  (ws + 333119488ull); // 307,494,912
    float* h1    = (float*)(ws + 640614400ull); // 25,165,824
    u16*   hbf   = (u16*)  (ws + 665780224ull); // 12,582,912
    u16*   h2b   = (u16*)  (ws + 678363136ull); // 12,582,912
    u16*   web   = (u16*)  (ws + 690946048ull); // 1,277,952
    u16*   w1b   = (u16*)  (ws + 692224000ull); // 1,179,648
    u16*   w2b   = (u16*)  (ws + 693403648ull); // 1,179,648
    int*   lidx  = (int*)  (ws + 694583296ull); // 800,000
    int*   eord  = (int*)  (ws + 695383296ull); // 800,000
    int*   counts= (int*)  (ws + 696183296ull); // 32,768
    int*   cursor= (int*)  (ws + 696216064ull); // 32,768
    int*   starts= (int*)  (ws + 696248832ull); // 32,776
    float* ssum  = (float*)(ws + 696281616ull); // 3,072
    float* ssq   = (float*)(ws + 696284688ull);
    float* scale = (float*)(ws + 696287760ull);
    float* shift = (float*)(ws + 696290832ull);

    hipMemsetAsync(counts, 0, 65536, stream);           // counts + cursor
    hipMemsetAsync(ssum, 0, 2 * D_N * 4, stream);       // ssum + ssq

    k_conv_wedge<<<(D_N * KP_E + 255) / 256, 256, 0, stream>>>(Wedge, web);
    k_conv_w<<<(D_N * D_N + 255) / 256, 256, 0, stream>>>(W1, w1b, D_N * D_N);
    k_conv_w<<<(D_N * D_N + 255) / 256, 256, 0, stream>>>(W2, w2b, D_N * D_N);

    k_localidx<<<(E_N + 255) / 256, 256, 0, stream>>>(uniq, srcg, lidx);
    k_hist<<<(E_N + 255) / 256, 256, 0, stream>>>(lidx, counts);
    k_scan<<<1, 1024, 0, stream>>>(counts, starts);
    k_scatter<<<(E_N + 255) / 256, 256, 0, stream>>>(lidx, starts, cursor, eord);

    k_pack<<<(int)(((long long)E_N * 104 + 255) / 256), 256, 0, stream>>>(tgt, edg, Abf);

    gemm_edge2<<<8 * 196 * 6, 256, 0, stream>>>(Abf, web, bedge, msgs);

    k_gather<<<U_N, 384, 0, stream>>>(msgs, starts, eord, x, epsp, hbf);

    gemm_bf16_g<<<(U_N / 128) * 6, 256, 0, stream>>>(hbf, w1b, h1, 6, D_N);

    k_bnstats<<<96, 256, 0, stream>>>(h1, ssum, ssq);
    k_bnfinal<<<3, 256, 0, stream>>>(ssum, ssq, gamma, beta, scale, shift);
    k_bnapply<<<(U_N * D_N + 255) / 256, 256, 0, stream>>>(h1, scale, shift, h2b);

    gemm_bf16_g<<<(U_N / 128) * 6, 256, 0, stream>>>(h2b, w2b, out, 6, D_N);
  } else {
    // ---------- fallback: round-1 path ----------
    float* agg   = (float*)(ws + 0);
    float* h1    = (float*)(ws + 25165824);
    u16*   web   = (u16*)  (ws + 50331648);
    u16*   w1b   = (u16*)  (ws + 51609600);
    u16*   w2b   = (u16*)  (ws + 52789248);
    u16*   hbf   = (u16*)  (ws + 53968896);
    u16*   h2b   = (u16*)  (ws + 66551808);
    int*   lidx  = (int*)  (ws + 79134720);
    float* ssum  = (float*)(ws + 79934720);
    float* ssq   = (float*)(ws + 79937792);
    float* scale = (float*)(ws + 79940864);
    float* shift = (float*)(ws + 79943936);

    hipMemsetAsync(agg, 0, (size_t)U_N * D_N * 4, stream);
    hipMemsetAsync(ssum, 0, 2 * D_N * 4, stream);

    k_localidx<<<(E_N + 255) / 256, 256, 0, stream>>>(uniq, srcg, lidx);
    k_conv_wedge<<<(D_N * KP_E + 255) / 256, 256, 0, stream>>>(Wedge, web);
    k_conv_w<<<(D_N * D_N + 255) / 256, 256, 0, stream>>>(W1, w1b, D_N * D_N);
    k_conv_w<<<(D_N * D_N + 255) / 256, 256, 0, stream>>>(W2, w2b, D_N * D_N);
    gemm_edge_fb<<<1563 * 6, 256, 0, stream>>>(tgt, edg, web, bedge, lidx, agg);
    k_build_h<<<(U_N * D_N + 255) / 256, 256, 0, stream>>>(x, agg, epsp, hbf);
    gemm_bf16_fb<<<(U_N / 128) * (D_N / 128), 256, 0, stream>>>(hbf, w1b, h1, U_N, D_N, D_N);
    k_bnstats<<<96, 256, 0, stream>>>(h1, ssum, ssq);
    k_bnfinal<<<3, 256, 0, stream>>>(ssum, ssq, gamma, beta, scale, shift);
    k_bnapply<<<(U_N * D_N + 255) / 256, 256, 0, stream>>>(h1, scale, shift, h2b);
    gemm_bf16_fb<<<(U_N / 128) * (D_N / 128), 256, 0, stream>>>(h2b, w2b, out, U_N, D_N, D_N);
  }
}

// Round 3
// 828.133 us; speedup vs baseline: 1.6629x; 1.0575x over previous
//
#include <hip/hip_runtime.h>
#include <stdint.h>
#include <math.h>

typedef unsigned short u16;
typedef __attribute__((ext_vector_type(4))) float f32x4;
typedef __attribute__((ext_vector_type(8))) short s16x8;

#define U_N 8192
#define E_N 200000
#define M_PAD 200192   // 782 * 256
#define D_N 768
#define DE_N 50
#define KP_E 832
#define NT_E 26        // 832 / 32
#define BN_EPS 1e-5f

__device__ __forceinline__ u16 f2bf(float f) {
  union { float f; unsigned u; } v; v.f = f;
  return (u16)((v.u + 0x7fffu + ((v.u >> 16) & 1u)) >> 16);
}
__device__ __forceinline__ float bf2f(u16 v) {
  union { unsigned u; float f; } x; x.u = ((unsigned)v) << 16; return x.f;
}
__device__ __forceinline__ void gload16(const void* g, void* l) {
  __builtin_amdgcn_global_load_lds((const __attribute__((address_space(1))) void*)g,
                                   (__attribute__((address_space(3))) void*)l, 16, 0, 0);
}

// ---------------- searchsorted (left) ----------------
__global__ void k_localidx(const int* __restrict__ uniq, const int* __restrict__ src,
                           int* __restrict__ lidx) {
  int e = blockIdx.x * 256 + threadIdx.x;
  if (e >= E_N) return;
  int v = src[e];
  int lo = 0, hi = U_N;
  while (lo < hi) { int mid = (lo + hi) >> 1; if (uniq[mid] < v) lo = mid + 1; else hi = mid; }
  lidx[e] = lo;
}

// ---------------- counting sort: hist / scan / scatter ----------------
__global__ void k_hist(const int* __restrict__ lidx, int* __restrict__ counts) {
  int e = blockIdx.x * 256 + threadIdx.x;
  if (e < E_N) atomicAdd(&counts[lidx[e]], 1);
}

__global__ void k_scan(const int* __restrict__ counts, int* __restrict__ starts) {
  __shared__ int part[1024];
  const int t = threadIdx.x;
  const int base = t * 8;
  int loc[8]; int s = 0;
#pragma unroll
  for (int i = 0; i < 8; i++) { loc[i] = s; s += counts[base + i]; }
  part[t] = s; __syncthreads();
  for (int off = 1; off < 1024; off <<= 1) {
    int v = (t >= off) ? part[t - off] : 0;
    __syncthreads();
    part[t] += v;
    __syncthreads();
  }
  const int pre = (t == 0) ? 0 : part[t - 1];
#pragma unroll
  for (int i = 0; i < 8; i++) starts[base + i] = pre + loc[i];
  if (t == 1023) starts[8192] = pre + s;
}

__global__ void k_scatter(const int* __restrict__ lidx, const int* __restrict__ starts,
                          int* __restrict__ cursor, int* __restrict__ eord) {
  int e = blockIdx.x * 256 + threadIdx.x;
  if (e >= E_N) return;
  int u = lidx[e];
  int pos = atomicAdd(&cursor[u], 1);
  eord[starts[u] + pos] = e;
}

// ---------------- pack A: [E][832] bf16, concat(tgt, edg, 0-pad) ----------------
__global__ void k_pack(const float* __restrict__ tgt, const float* __restrict__ edg,
                       u16* __restrict__ Abf) {
  const long long g = (long long)blockIdx.x * 256 + threadIdx.x;
  if (g >= (long long)E_N * 104) return;
  const int e = (int)(g / 104), seg = (int)(g % 104);
  const int c0 = seg * 8;
  s16x8 v = {};
  if (c0 + 8 <= D_N) {
    const f32x4 f0 = *(const f32x4*)(tgt + (size_t)e * D_N + c0);
    const f32x4 f1 = *(const f32x4*)(tgt + (size_t)e * D_N + c0 + 4);
#pragma unroll
    for (int z = 0; z < 4; z++) { v[z] = (short)f2bf(f0[z]); v[4 + z] = (short)f2bf(f1[z]); }
  } else {
#pragma unroll
    for (int z = 0; z < 8; z++) {
      const int kk = c0 + z - D_N;
      v[z] = (short)f2bf(kk < DE_N ? edg[(size_t)e * DE_N + kk] : 0.f);
    }
  }
  *(s16x8*)&Abf[(size_t)e * KP_E + c0] = v;
}

// ---------------- weight conversions ----------------
__global__ void k_conv_wedge(const float* __restrict__ W, u16* __restrict__ Wb) {
  int i = blockIdx.x * 256 + threadIdx.x;
  if (i >= D_N * KP_E) return;
  int n = i / KP_E, k = i % KP_E;
  float f = (k < D_N + DE_N) ? W[n * (D_N + DE_N) + k] : 0.f;
  Wb[i] = f2bf(f);
}

__global__ void k_conv_w(const float* __restrict__ W, u16* __restrict__ Wb, int count) {
  int i = blockIdx.x * 256 + threadIdx.x;
  if (i < count) Wb[i] = f2bf(W[i]);
}

// =========== edge GEMM v3: 256x256 tile, BK=32, 4-deep ring, counted vmcnt ===========
// LDS ring: 4 buffers x (A 256x32 + B 256x32) bf16 = 128 KiB.
// Per iter t: vmcnt(8); s_barrier; STAGE(t+3) [4 gload_lds]; compute tile t [12 ds_read_b128, 32 MFMA].
// Swizzle (both sides, rule #21): lds 16B-slot s at row r holds global slot s ^ ((r>>1)&3).
__global__ __launch_bounds__(512)
void gemm_edge3(const u16* __restrict__ Abf, const u16* __restrict__ Wb,
                const float* __restrict__ bias, u16* __restrict__ msgs) {
  __shared__ u16 As[4][256 * 32];
  __shared__ u16 Bs[4][256 * 32];

  // bijective XCD swizzle (m204), nwg = 782*3 = 2346, q=293, r=2
  const int orig = blockIdx.x;
  const int xcd = orig & 7, i8 = orig >> 3;
  const int wgid = (xcd < 2 ? xcd * 294 : 2 * 294 + (xcd - 2) * 293) + i8;
  const int bm = (wgid / 3) * 256;
  const int bn = (wgid % 3) * 256;

  const int tid = threadIdx.x;
  const int w = tid >> 6, lane = tid & 63;
  const int wm = w >> 2, wn = w & 3;          // wave tile: rows wm*128, cols wn*64
  const int rl = lane & 15, K16 = lane >> 4;  // fragment lane decode
  const int sws = ((K16 ^ ((rl >> 1) & 3)) << 3);  // swizzled k-slot (u16 units)

  // staging decode: chunk c = w*2+q (16 rows each), lane -> row l>>2, slot l&3
  const int srow = lane >> 2;
  const int sslot = lane & 3;
  const int sg = sslot ^ ((srow >> 1) & 3);   // (r>>1)&3 == (srow>>1)&3 since chunk*16 ≡ 0 mod 8

  f32x4 acc[8][4] = {};

#define STAGE(T)                                                                        \
  {                                                                                     \
    const int b_ = (T) & 3;                                                             \
    const int k0_ = (T) * 32;                                                           \
    _Pragma("unroll")                                                                   \
    for (int q_ = 0; q_ < 2; ++q_) {                                                    \
      const int c_ = w * 2 + q_;                                                        \
      const int r_ = c_ * 16 + srow;                                                    \
      gload16(Abf + (size_t)(bm + r_) * KP_E + k0_ + sg * 8, &As[b_][c_ * 512]);        \
    }                                                                                   \
    _Pragma("unroll")                                                                   \
    for (int q_ = 0; q_ < 2; ++q_) {                                                    \
      const int c_ = w * 2 + q_;                                                        \
      const int r_ = c_ * 16 + srow;                                                    \
      gload16(Wb + (size_t)(bn + r_) * KP_E + k0_ + sg * 8, &Bs[b_][c_ * 512]);         \
    }                                                                                   \
  }

#define COMPUTE(BB)                                                                     \
  {                                                                                     \
    const int b_ = (BB);                                                                \
    s16x8 bfrag[4];                                                                     \
    _Pragma("unroll")                                                                   \
    for (int j_ = 0; j_ < 4; ++j_) {                                                    \
      const int R_ = wn * 64 + j_ * 16 + rl;                                            \
      bfrag[j_] = *(const s16x8*)&Bs[b_][R_ * 32 + sws];                                \
    }                                                                                   \
    s16x8 afrag[4];                                                                     \
    _Pragma("unroll")                                                                   \
    for (int i_ = 0; i_ < 4; ++i_) {                                                    \
      const int R_ = wm * 128 + i_ * 16 + rl;                                           \
      afrag[i_] = *(const s16x8*)&As[b_][R_ * 32 + sws];                                \
    }                                                                                   \
    __builtin_amdgcn_s_setprio(1);                                                      \
    _Pragma("unroll")                                                                   \
    for (int i_ = 0; i_ < 4; ++i_)                                                      \
      _Pragma("unroll")                                                                 \
      for (int j_ = 0; j_ < 4; ++j_)                                                    \
        acc[i_][j_] = __builtin_amdgcn_mfma_f32_16x16x32_bf16(afrag[i_], bfrag[j_],     \
                                                              acc[i_][j_], 0, 0, 0);   \
    __builtin_amdgcn_s_setprio(0);                                                      \
    _Pragma("unroll")                                                                   \
    for (int i_ = 0; i_ < 4; ++i_) {                                                    \
      const int R_ = wm * 128 + (4 + i_) * 16 + rl;                                     \
      afrag[i_] = *(const s16x8*)&As[b_][R_ * 32 + sws];                                \
    }                                                                                   \
    __builtin_amdgcn_s_setprio(1);                                                      \
    _Pragma("unroll")                                                                   \
    for (int i_ = 0; i_ < 4; ++i_)                                                      \
      _Pragma("unroll")                                                                 \
      for (int j_ = 0; j_ < 4; ++j_)                                                    \
        acc[4 + i_][j_] = __builtin_amdgcn_mfma_f32_16x16x32_bf16(afrag[i_], bfrag[j_], \
                                                                  acc[4 + i_][j_], 0, 0, 0); \
    __builtin_amdgcn_s_setprio(0);                                                      \
  }

  // prologue: stage tiles 0,1,2 (12 loads in flight per thread)
  STAGE(0)
  STAGE(1)
  STAGE(2)

  for (int t = 0; t < NT_E - 3; ++t) {
    asm volatile("s_waitcnt vmcnt(8)");
    __builtin_amdgcn_s_barrier();
    asm volatile("" ::: "memory");
    STAGE(t + 3)
    COMPUTE(t & 3)
  }
  // t = 23 (buf 3): tiles 24,25 in flight (8)
  asm volatile("s_waitcnt vmcnt(8)");
  __builtin_amdgcn_s_barrier();
  asm volatile("" ::: "memory");
  COMPUTE(3)
  // t = 24 (buf 0): tile 25 in flight (4)
  asm volatile("s_waitcnt vmcnt(4)");
  __builtin_amdgcn_s_barrier();
  asm volatile("" ::: "memory");
  COMPUTE(0)
  // t = 25 (buf 1): drain
  asm volatile("s_waitcnt vmcnt(0)");
  __builtin_amdgcn_s_barrier();
  asm volatile("" ::: "memory");
  COMPUTE(1)

#undef STAGE
#undef COMPUTE

  // epilogue: relu(acc + bias) -> bf16 msgs
  const int rq = (lane >> 4) * 4;
  const int cl = lane & 15;
#pragma unroll
  for (int j = 0; j < 4; ++j) {
    const int col = bn + wn * 64 + j * 16 + cl;
    const float bj = bias[col];
#pragma unroll
    for (int mf = 0; mf < 8; ++mf) {
      const int r0 = bm + wm * 128 + mf * 16 + rq;
#pragma unroll
      for (int q = 0; q < 4; ++q) {
        const float v = acc[mf][j][q] + bj;
        msgs[(size_t)(r0 + q) * D_N + col] = f2bf(v > 0.f ? v : 0.f);
      }
    }
  }
}

// ---------------- gather: h = (1+eps)*x + segment_sum(msgs) -> bf16 ----------------
__global__ __launch_bounds__(384)
void k_gather(const u16* __restrict__ msgs, const int* __restrict__ starts,
              const int* __restrict__ eord, const float* __restrict__ x,
              const float* __restrict__ epsp, u16* __restrict__ hbf) {
  const int u = blockIdx.x;
  const int c2 = threadIdx.x;
  const int s = starts[u], e = starts[u + 1];
  float a0 = 0.f, a1 = 0.f;
  for (int i = s; i < e; i++) {
    const unsigned v = *(const unsigned*)&msgs[(size_t)eord[i] * D_N + c2 * 2];
    a0 += bf2f((u16)(v & 0xffffu));
    a1 += bf2f((u16)(v >> 16));
  }
  const float ep = 1.f + epsp[0];
  const float2 xv = *(const float2*)&x[(size_t)u * D_N + c2 * 2];
  const unsigned o = ((unsigned)f2bf(ep * xv.y + a1) << 16) | (unsigned)f2bf(ep * xv.x + a0);
  *(unsigned*)&hbf[(size_t)u * D_N + c2 * 2] = o;
}

// ---------------- generic bf16 GEMM (m97 structure), C f32 [M][N], K%64==0 ----------------
__global__ __launch_bounds__(256)
void gemm_bf16_g(const u16* __restrict__ A, const u16* __restrict__ B,
                 float* __restrict__ C, int ntn, int K) {
  __shared__ u16 As[128 * 64];
  __shared__ u16 Bs[128 * 64];
  const int bm = (blockIdx.x / ntn) * 128;
  const int bn = (blockIdx.x % ntn) * 128;
  const int t = threadIdx.x;
  const int wave = t >> 6, lane = t & 63;
  const int wr = (wave & 1) * 64, wc = (wave >> 1) * 64;
  const int srow = lane >> 3, scol = (lane & 7) * 8;
  const int rl = lane & 15, kl = (lane >> 4) * 8;
  const int N = ntn * 128;
  f32x4 acc[4][4] = {};
  for (int k0 = 0; k0 < K; k0 += 64) {
#pragma unroll
    for (int q = 0; q < 4; q++) {
      const int c = wave * 4 + q;
      const int row = c * 8 + srow;
      gload16(A + (size_t)(bm + row) * K + k0 + scol, As + c * 512);
      gload16(B + (size_t)(bn + row) * K + k0 + scol, Bs + c * 512);
    }
    __syncthreads();
#pragma unroll
    for (int ks = 0; ks < 2; ks++) {
      s16x8 af[4], bfr[4];
#pragma unroll
      for (int i = 0; i < 4; i++) af[i] = *(const s16x8*)&As[(wr + i * 16 + rl) * 64 + ks * 32 + kl];
#pragma unroll
      for (int j = 0; j < 4; j++) bfr[j] = *(const s16x8*)&Bs[(wc + j * 16 + rl) * 64 + ks * 32 + kl];
#pragma unroll
      for (int i = 0; i < 4; i++)
#pragma unroll
        for (int j = 0; j < 4; j++)
          acc[i][j] = __builtin_amdgcn_mfma_f32_16x16x32_bf16(af[i], bfr[j], acc[i][j], 0, 0, 0);
    }
    __syncthreads();
  }
  const int cl = lane & 15, rq = (lane >> 4) * 4;
#pragma unroll
  for (int i = 0; i < 4; i++)
#pragma unroll
    for (int j = 0; j < 4; j++) {
      const int n = bn + wc + j * 16 + cl;
      const int r = bm + wr + i * 16 + rq;
#pragma unroll
      for (int q = 0; q < 4; q++)
        C[(size_t)(r + q) * N + n] = acc[i][j][q];
    }
}

// ---------------- BN ----------------
__global__ void k_bnstats(const float* __restrict__ h1, float* __restrict__ ssum,
                          float* __restrict__ ssq) {
  const int cchunk = blockIdx.x % 3;
  const int rchunk = blockIdx.x / 3;
  const int c = cchunk * 256 + threadIdx.x;
  const int r0 = rchunk * 256;
  float s = 0.f, s2 = 0.f;
  for (int r = r0; r < r0 + 256; r++) {
    float v = h1[(size_t)r * D_N + c];
    s += v; s2 += v * v;
  }
  atomicAdd(&ssum[c], s);
  atomicAdd(&ssq[c], s2);
}

__global__ void k_bnfinal(const float* __restrict__ ssum, const float* __restrict__ ssq,
                          const float* __restrict__ gamma, const float* __restrict__ beta,
                          float* __restrict__ scale, float* __restrict__ shift) {
  int c = blockIdx.x * 256 + threadIdx.x;
  if (c >= D_N) return;
  double mean = (double)ssum[c] / (double)U_N;
  double var = (double)ssq[c] / (double)U_N - mean * mean;
  float sc = (float)((double)gamma[c] / sqrt(var + (double)BN_EPS));
  scale[c] = sc;
  shift[c] = beta[c] - (float)mean * sc;
}

__global__ void k_bnapply(const float* __restrict__ h1, const float* __restrict__ scale,
                          const float* __restrict__ shift, u16* __restrict__ h2) {
  int i = blockIdx.x * 256 + threadIdx.x;
  if (i >= U_N * D_N) return;
  int c = i % D_N;
  float v = h1[i] * scale[c] + shift[c];
  h2[i] = f2bf(v > 0.f ? v : 0.f);
}

extern "C" void kernel_launch(void* const* d_in, const int* in_sizes, int n_in,
                              void* d_out, int out_size, void* d_ws, size_t ws_size,
                              hipStream_t stream) {
  const float* x     = (const float*)d_in[0];
  const int*   uniq  = (const int*)d_in[1];
  const int*   srcg  = (const int*)d_in[2];
  const float* tgt   = (const float*)d_in[3];
  const float* edg   = (const float*)d_in[4];
  const float* Wedge = (const float*)d_in[5];
  const float* bedge = (const float*)d_in[6];
  const float* W1    = (const float*)d_in[7];
  const float* W2    = (const float*)d_in[8];
  const float* gamma = (const float*)d_in[9];
  const float* beta  = (const float*)d_in[10];
  const float* epsp  = (const float*)d_in[11];
  float* out = (float*)d_out;
  char* ws = (char*)d_ws;

  u16*   Abf   = (u16*)  (ws + 0);            // 333,119,488
  u16*   msgs  = (u16*)  (ws + 333119488ull); // 307,494,912
  float* h1    = (float*)(ws + 640614400ull); // 25,165,824
  u16*   hbf   = (u16*)  (ws + 665780224ull); // 12,582,912
  u16*   h2b   = (u16*)  (ws + 678363136ull); // 12,582,912
  u16*   web   = (u16*)  (ws + 690946048ull); // 1,277,952
  u16*   w1b   = (u16*)  (ws + 692224000ull); // 1,179,648
  u16*   w2b   = (u16*)  (ws + 693403648ull); // 1,179,648
  int*   lidx  = (int*)  (ws + 694583296ull); // 800,000
  int*   eord  = (int*)  (ws + 695383296ull); // 800,000
  int*   counts= (int*)  (ws + 696183296ull); // 32,768
  int*   cursor= (int*)  (ws + 696216064ull); // 32,768
  int*   starts= (int*)  (ws + 696248832ull); // 32,776
  float* ssum  = (float*)(ws + 696281616ull); // 3,072
  float* ssq   = (float*)(ws + 696284688ull);
  float* scale = (float*)(ws + 696287760ull);
  float* shift = (float*)(ws + 696290832ull);

  hipMemsetAsync(counts, 0, 65536, stream);           // counts + cursor
  hipMemsetAsync(ssum, 0, 2 * D_N * 4, stream);       // ssum + ssq

  k_conv_wedge<<<(D_N * KP_E + 255) / 256, 256, 0, stream>>>(Wedge, web);
  k_conv_w<<<(D_N * D_N + 255) / 256, 256, 0, stream>>>(W1, w1b, D_N * D_N);
  k_conv_w<<<(D_N * D_N + 255) / 256, 256, 0, stream>>>(W2, w2b, D_N * D_N);

  k_localidx<<<(E_N + 255) / 256, 256, 0, stream>>>(uniq, srcg, lidx);
  k_hist<<<(E_N + 255) / 256, 256, 0, stream>>>(lidx, counts);
  k_scan<<<1, 1024, 0, stream>>>(counts, starts);
  k_scatter<<<(E_N + 255) / 256, 256, 0, stream>>>(lidx, starts, cursor, eord);

  k_pack<<<(int)(((long long)E_N * 104 + 255) / 256), 256, 0, stream>>>(tgt, edg, Abf);

  // 782 M-tiles x 3 N-tiles, 512 threads, 128 KiB LDS ring
  gemm_edge3<<<782 * 3, 512, 0, stream>>>(Abf, web, bedge, msgs);

  k_gather<<<U_N, 384, 0, stream>>>(msgs, starts, eord, x, epsp, hbf);

  gemm_bf16_g<<<(U_N / 128) * 6, 256, 0, stream>>>(hbf, w1b, h1, 6, D_N);

  k_bnstats<<<96, 256, 0, stream>>>(h1, ssum, ssq);
  k_bnfinal<<<3, 256, 0, stream>>>(ssum, ssq, gamma, beta, scale, shift);
  k_bnapply<<<(U_N * D_N + 255) / 256, 256, 0, stream>>>(h1, scale, shift, h2b);

  gemm_bf16_g<<<(U_N / 128) * 6, 256, 0, stream>>>(h2b, w2b, out, 6, D_N);
}